// Round 25
// baseline (223.136 us; speedup 1.0000x reference)
//
#include <hip/hip_runtime.h>
#include <math.h>

#define BB 2
#define TT 1024
#define DD 1536
#define HH 12
#define TQK 768
#define TVv 1536
#define CQKV 3072
#define NQKVG 4608
#define EPSF 1e-6f
#define NBH (BB * HH)   // 24

// scratch swizzle: row-linear, 16B chunks XOR'd by row&7 (conflict-free b128)
#define SWZ(row, col) ((row) * 64 + ((((col) >> 3) ^ ((row) & 7)) << 3) + ((col) & 7))

typedef __attribute__((ext_vector_type(8))) _Float16 half8v;
typedef __attribute__((ext_vector_type(4))) float f32x4;

__device__ __forceinline__ float siluf(float x) { return x / (1.f + expf(-x)); }

__device__ __forceinline__ uint pk2h(float a, float b) {
  union { _Float16 h[2]; uint u; } p;
  p.h[0] = (_Float16)a; p.h[1] = (_Float16)b;
  return p.u;
}
__device__ __forceinline__ ushort f2h(float f) {
  _Float16 h = (_Float16)f; ushort u; __builtin_memcpy(&u, &h, 2); return u;
}
__device__ __forceinline__ float h2f(ushort u) {
  _Float16 h; __builtin_memcpy(&h, &u, 2); return (float)h;
}

// async global->LDS
__device__ __forceinline__ void gload16(const void* g, void* l) {
  __builtin_amdgcn_global_load_lds(
      (const __attribute__((address_space(1))) void*)g,
      (__attribute__((address_space(3))) void*)l, 16, 0, 0);
}

// ---------------------------------------------------------------------------
// fp16 MFMA GEMM, K-split, compile-time dims + bijective XCD swizzle.
// ---------------------------------------------------------------------------
template <int K, int KS, int Z>
__global__ __launch_bounds__(256) void gemm_f16_ks(
    const ushort* __restrict__ X, const ushort* __restrict__ W,
    ushort* __restrict__ P, int M, int N)
{
  __shared__ ushort Ah[128 * 64];
  __shared__ ushort Bh[128 * 64];
  const int tid  = threadIdx.x;
  const int lane = tid & 63;
  const int w    = tid >> 6;
  const int wr   = w >> 1, wc = w & 1;

  const int nwg = gridDim.x;
  const int i0  = blockIdx.x;
  const int wk  = (i0 & 7) * (nwg >> 3) + (i0 >> 3);
  const int ncz = (M >> 7) * Z;
  const int bx  = wk / ncz;
  const int rem = wk % ncz;
  const int by  = rem / Z;
  const int z   = rem % Z;

  const int r0  = by * 128, c0 = bx * 128;
  const int k0b = z * KS;
  ushort* Pz = P + (size_t)z * M * N;

  const int dr   = lane >> 3;
  const int slot = (lane & 7) ^ dr;

  f32x4 acc[4][4];
#pragma unroll
  for (int m = 0; m < 4; ++m)
#pragma unroll
    for (int n = 0; n < 4; ++n)
#pragma unroll
      for (int j = 0; j < 4; ++j) acc[m][n][j] = 0.f;

#pragma unroll
  for (int ki = 0; ki < KS / 64; ++ki) {
    const int k0 = k0b + ki * 64;
#pragma unroll
    for (int j = 0; j < 4; ++j) {
      const int row  = (w * 4 + j) * 8 + dr;
      const size_t xo = (size_t)(r0 + row) * K + k0 + slot * 8;
      const size_t wo = (size_t)(c0 + row) * K + k0 + slot * 8;
      const int ldso = (w * 4 + j) * 512;
      gload16(X + xo, Ah + ldso);
      gload16(W + wo, Bh + ldso);
    }
    __syncthreads();
#pragma unroll
    for (int kk = 0; kk < 2; ++kk) {
      const int kc8 = kk * 4 + (lane >> 4);
      const int sw  = (kc8 ^ (lane & 7)) << 3;
      half8v a[4], b[4];
#pragma unroll
      for (int m = 0; m < 4; ++m)
        a[m] = *(const half8v*)(Ah + (wr * 64 + m * 16 + (lane & 15)) * 64 + sw);
#pragma unroll
      for (int n = 0; n < 4; ++n)
        b[n] = *(const half8v*)(Bh + (wc * 64 + n * 16 + (lane & 15)) * 64 + sw);
#pragma unroll
      for (int m = 0; m < 4; ++m)
#pragma unroll
        for (int n = 0; n < 4; ++n)
          acc[m][n] = __builtin_amdgcn_mfma_f32_16x16x32_f16(a[m], b[n], acc[m][n], 0, 0, 0);
    }
    __syncthreads();
  }

  const int crow = (lane >> 4) * 4;
  const int ccol = lane & 15;
#pragma unroll
  for (int m = 0; m < 4; ++m)
#pragma unroll
    for (int j = 0; j < 4; ++j) {
      ushort* cp = Pz + (size_t)(r0 + wr * 64 + m * 16 + crow + j) * N + c0 + wc * 64 + ccol;
#pragma unroll
      for (int n = 0; n < 4; ++n) cp[n * 16] = f2h(acc[m][n][j]);
    }
}

// ---------------------------------------------------------------------------
// f32 -> fp16 casts.
// ---------------------------------------------------------------------------
__device__ __forceinline__ void cast8_store(const float* f, ushort* dst, size_t e)
{
  uint4 pk;
  pk.x = pk2h(f[0], f[1]); pk.y = pk2h(f[2], f[3]);
  pk.z = pk2h(f[4], f[5]); pk.w = pk2h(f[6], f[7]);
  *(uint4*)(dst + e) = pk;
}

__global__ void cast_f16_kernel(const float* __restrict__ src, ushort* __restrict__ dst)
{
  int cid = blockIdx.x * blockDim.x + threadIdx.x;
  size_t e = (size_t)cid * 8;
  float f[8];
  *(float4*)(f)     = *(const float4*)(src + e);
  *(float4*)(f + 4) = *(const float4*)(src + e + 4);
  cast8_store(f, dst, e);
}

__global__ void cast_w4_kernel(const float* __restrict__ wq, const float* __restrict__ wk,
                               const float* __restrict__ wv, const float* __restrict__ wg,
                               ushort* __restrict__ dst)
{
  int cid = blockIdx.x * blockDim.x + threadIdx.x;
  size_t e = (size_t)cid * 8;
  const float* src; size_t off;
  if (e < 1179648)      { src = wq; off = e; }
  else if (e < 2359296) { src = wk; off = e - 1179648; }
  else if (e < 4718592) { src = wv; off = e - 2359296; }
  else                  { src = wg; off = e - 4718592; }
  float f[8];
  *(float4*)(f)     = *(const float4*)(src + off);
  *(float4*)(f + 4) = *(const float4*)(src + off + 4);
  cast8_store(f, dst, e);
}

// ---------------------------------------------------------------------------
// Causal depthwise conv (K=4) + SiLU + fused L2-norm + fused g-fold,
// VECTORIZED: 8 consecutive columns per thread (half8v loads/stores).
// 576 col-groups/row; wave = 64 groups = 8 aligned heads; 8 lanes = 1 head
// -> per-thread partial + 3-level shfl_xor for the L2 norm.
// ---------------------------------------------------------------------------
__global__ void conv_silu_kernel(
    const ushort* __restrict__ pA, const ushort* __restrict__ pB,
    const float* __restrict__ qw, const float* __restrict__ kw, const float* __restrict__ vw,
    ushort* __restrict__ qc, ushort* __restrict__ kc, ushort* __restrict__ vc,
    ushort* __restrict__ g16)
{
  const int idx = blockIdx.x * blockDim.x + threadIdx.x;   // < 2048*576
  const int c8  = idx % 576;
  const int bt  = idx / 576;
  const int t   = bt % TT;
  const int b   = bt / TT;
  const int c   = c8 * 8;

  if (c >= CQKV) {   // g columns: fold the two partials
    size_t ii = (size_t)bt * NQKVG + c;
    half8v a = *(const half8v*)(pA + ii);
    half8v bb = *(const half8v*)(pB + ii);
    half8v r;
#pragma unroll
    for (int e = 0; e < 8; ++e) r[e] = (_Float16)((float)a[e] + (float)bb[e]);
    *(half8v*)(g16 + (size_t)bt * TVv + (c - CQKV)) = r;
    return;
  }

  const float* wbase = (c < TQK)     ? qw + (size_t)c * 4
                     : (c < 2 * TQK) ? kw + (size_t)(c - TQK) * 4
                                     : vw + (size_t)(c - 2 * TQK) * 4;

  float s[8];
#pragma unroll
  for (int e = 0; e < 8; ++e) s[e] = 0.f;
#pragma unroll
  for (int j = 0; j < 4; ++j) {
    const int ts = t - 3 + j;
    if (ts >= 0) {
      size_t ii = (size_t)(b * TT + ts) * NQKVG + c;
      half8v a = *(const half8v*)(pA + ii);
      half8v bb = *(const half8v*)(pB + ii);
#pragma unroll
      for (int e = 0; e < 8; ++e)
        s[e] = fmaf((float)a[e] + (float)bb[e], wbase[e * 4 + j], s[e]);
    }
  }
#pragma unroll
  for (int e = 0; e < 8; ++e) s[e] = siluf(s[e]);

  if (c < 2 * TQK) {     // q/k: L2 norm over the head (8 lanes x 8 elems)
    float ss = 0.f;
#pragma unroll
    for (int e = 0; e < 8; ++e) ss = fmaf(s[e], s[e], ss);
    ss += __shfl_xor(ss, 1);
    ss += __shfl_xor(ss, 2);
    ss += __shfl_xor(ss, 4);
    const float inv = 1.f / fmaxf(sqrtf(ss), EPSF);
#pragma unroll
    for (int e = 0; e < 8; ++e) s[e] *= inv;
  }

  half8v r;
#pragma unroll
  for (int e = 0; e < 8; ++e) r[e] = (_Float16)s[e];

  if (c < TQK) {
    const int h = c >> 6, d = c & 63;
    *(half8v*)(qc + ((size_t)(b * HH + h) * TT + t) * 64 + d) = r;
  } else if (c < 2 * TQK) {
    const int c2 = c - TQK; const int h = c2 >> 6, d = c2 & 63;
    *(half8v*)(kc + ((size_t)(b * HH + h) * TT + t) * 64 + d) = r;
  } else {
    const int c2 = c - 2 * TQK; const int h = c2 >> 7, d = c2 & 127;
    *(half8v*)(vc + ((size_t)(b * HH + h) * TT + t) * 128 + d) = r;
  }
}

// ---------------------------------------------------------------------------
// reduce4: d_out = sum of 4 f16 partials of the final GEMM.
// ---------------------------------------------------------------------------
__global__ void reduce4_kernel(const ushort* __restrict__ p, float* __restrict__ out)
{
  int cid = blockIdx.x * blockDim.x + threadIdx.x;
  size_t e = (size_t)cid * 8;
  float acc8[8];
#pragma unroll
  for (int i = 0; i < 8; ++i) acc8[i] = 0.f;
#pragma unroll
  for (int part = 0; part < 4; ++part) {
    half8v v = *(const half8v*)(p + (size_t)part * 3145728 + e);
#pragma unroll
    for (int i = 0; i < 8; ++i) acc8[i] += (float)v[i];
  }
  *(float4*)(out + e)     = make_float4(acc8[0], acc8[1], acc8[2], acc8[3]);
  *(float4*)(out + e + 4) = make_float4(acc8[4], acc8[5], acc8[6], acc8[7]);
}

// ---------------------------------------------------------------------------
// Gating: block per row; x row staged in LDS once.
// ---------------------------------------------------------------------------
__global__ __launch_bounds__(256) void gate_kernel(
    const float* __restrict__ x, const float* __restrict__ w_a, const float* __restrict__ w_b,
    const float* __restrict__ A_log, const float* __restrict__ dt_bias,
    float* __restrict__ abi)
{
  __shared__ float xs[DD];
  const int m    = blockIdx.x;
  const int w    = threadIdx.x >> 6;
  const int lane = threadIdx.x & 63;
  const float* xr = x + (size_t)m * DD;
  for (int i = threadIdx.x; i < DD; i += 256) xs[i] = xr[i];
  __syncthreads();
  float xv[24];
#pragma unroll
  for (int i = 0; i < 24; ++i) xv[i] = xs[lane + i * 64];
  const int b = m / TT, t = m % TT;
#pragma unroll
  for (int j = 0; j < 6; ++j) {
    int o = w * 6 + j;
    bool isA = o < HH;
    int h = isA ? o : o - HH;
    const float* wr = (isA ? w_a : w_b) + (size_t)h * DD;
    float s = 0.f;
#pragma unroll
    for (int i = 0; i < 24; ++i) s = fmaf(xv[i], wr[lane + i * 64], s);
#pragma unroll
    for (int mm = 32; mm >= 1; mm >>= 1) s += __shfl_xor(s, mm, 64);
    if (lane == 0) {
      size_t idx = ((size_t)(b * HH + h) * TT + t) * 2;
      if (isA) {
        float a  = s + dt_bias[h];
        float sp = (a > 20.f) ? a : log1pf(expf(a));
        abi[idx] = expf(-expf(A_log[h]) * sp);
      } else {
        abi[idx + 1] = 2.f / (1.f + expf(-s));
      }
    }
  }
}

// ---------------------------------------------------------------------------
// Shared 64x64 MFMA GEMM helper: C = X @ Y^T.
// ---------------------------------------------------------------------------
__device__ __forceinline__ void gemm64(
    const _Float16* XB, int xstr, const _Float16* YB, int ystr,
    int wr, int wc, int lane, int ksteps, int kpad, f32x4 acc[2][2])
{
#pragma unroll
  for (int m = 0; m < 2; ++m)
#pragma unroll
    for (int n = 0; n < 2; ++n)
#pragma unroll
      for (int j = 0; j < 4; ++j) acc[m][n][j] = 0.f;
#pragma unroll 4
  for (int kk = 0; kk < ksteps; ++kk) {
    const int koff = kk * 32 + ((kk >> 1) ? kpad : 0) + (lane >> 4) * 8;
    half8v a[2], b[2];
#pragma unroll
    for (int m = 0; m < 2; ++m)
      a[m] = *(const half8v*)(XB + (wr * 32 + m * 16 + (lane & 15)) * xstr + koff);
#pragma unroll
    for (int n = 0; n < 2; ++n)
      b[n] = *(const half8v*)(YB + (wc * 32 + n * 16 + (lane & 15)) * ystr + koff);
#pragma unroll
    for (int m = 0; m < 2; ++m)
#pragma unroll
      for (int n = 0; n < 2; ++n)
        acc[m][n] = __builtin_amdgcn_mfma_f32_16x16x32_f16(a[m], b[n], acc[m][n], 0, 0, 0);
  }
}

// Swizzled-X variant (stride-64 XOR layout). ACCUMULATES into acc.
__device__ __forceinline__ void gemm64x(
    const ushort* XB, const _Float16* YB, int ystr,
    int wr, int wc, int lane, f32x4 acc[2][2])
{
#pragma unroll
  for (int kk = 0; kk < 2; ++kk) {
    const int cl = kk * 4 + (lane >> 4);
    half8v a[2], b[2];
#pragma unroll
    for (int m = 0; m < 2; ++m) {
      const int row = wr * 32 + m * 16 + (lane & 15);
      a[m] = *(const half8v*)((const _Float16*)XB + row * 64 + ((cl ^ (row & 7)) << 3));
    }
#pragma unroll
    for (int n = 0; n < 2; ++n)
      b[n] = *(const half8v*)(YB + (wc * 32 + n * 16 + (lane & 15)) * ystr + kk * 32 + (lane >> 4) * 8);
#pragma unroll
    for (int m = 0; m < 2; ++m)
#pragma unroll
      for (int n = 0; n < 2; ++n)
        acc[m][n] = __builtin_amdgcn_mfma_f32_16x16x32_f16(a[m], b[n], acc[m][n], 0, 0, 0);
  }
}

// ---------------------------------------------------------------------------
// Scan phase A (chunk-parallel, 384 blocks); SWZ scratch layout.
// ---------------------------------------------------------------------------
__global__ __launch_bounds__(256) void scan_phaseA(
    const ushort* __restrict__ qc, const ushort* __restrict__ kc,
    const ushort* __restrict__ vc, const float* __restrict__ abi,
    _Float16* __restrict__ SA, float* __restrict__ egCg)
{
  __shared__ _Float16 Kf[64 * 72];      // aliased as Tf after ph2
  __shared__ _Float16 Qf[64 * 72];
  __shared__ _Float16 KbT[64 * 72];
  __shared__ _Float16 VT[128 * 72];
  __shared__ float    Af[64 * 67];
  __shared__ float    Tg[64 * 67];
  __shared__ float    tmpf[1088];
  __shared__ float    g_s[64], bet_s[64], betg_s[64], eg_s[64], eKs_s[64];
  _Float16* Tf = Kf;

  const int unit = blockIdx.x;
  const int bh   = unit % NBH;
  const int c    = unit / NBH;
  const int c0   = c * 64;
  const int tid  = threadIdx.x;
  const int lane = tid & 63;
  const int w    = tid >> 6;
  const int wr   = w >> 1, wc = w & 1;

  _Float16* SAu = SA + (size_t)unit * 24576;

  if (tid < 64) {
    float2 ab = *(const float2*)(abi + ((size_t)bh * TT + c0 + tid) * 2);
    float gg = logf(ab.x);
#pragma unroll
    for (int off = 1; off < 64; off <<= 1) {
      float up = __shfl_up(gg, off, 64);
      if (tid >= off) gg += up;
    }
    float gC = __shfl(gg, 63, 64);
    g_s[tid]    = gg;
    bet_s[tid]  = ab.y;
    betg_s[tid] = ab.y * expf(gg);
    eg_s[tid]   = expf(gg);
    eKs_s[tid]  = expf(gC - gg);
    if (tid == 0) egCg[unit] = expf(gC);
  }
  __syncthreads();

  // ph1
  {
    const int t  = tid >> 2;
    const int dg = tid & 3;
    const ushort* krow = kc + ((size_t)bh * TT + c0 + t) * 64 + dg * 16;
    const ushort* qrow = qc + ((size_t)bh * TT + c0 + t) * 64 + dg * 16;
    const float bg = betg_s[t], egt = eg_s[t], ekt = eKs_s[t];
    half8v kva = *(const half8v*)(krow), kvb = *(const half8v*)(krow + 8);
    half8v qva = *(const half8v*)(qrow), qvb = *(const half8v*)(qrow + 8);
#pragma unroll
    for (int e = 0; e < 8; ++e) {
      const int d = dg * 16 + e;
      const float kf = (float)kva[e], qf = (float)qva[e];
      Kf[t * 72 + d]              = kva[e];
      KbT[d * 72 + t]             = (_Float16)(kf * bg);
      Qf[t * 72 + d]              = qva[e];
      SAu[8192 + SWZ(t, d)]       = (_Float16)(qf * egt);
      SAu[12288 + SWZ(d, t)]      = (_Float16)(kf * ekt);
    }
#pragma unroll
    for (int e = 0; e < 8; ++e) {
      const int d = dg * 16 + 8 + e;
      const float kf = (float)kvb[e], qf = (float)qvb[e];
      Kf[t * 72 + d]              = kvb[e];
      KbT[d * 72 + t]             = (_Float16)(kf * bg);
      Qf[t * 72 + d]              = qvb[e];
      SAu[8192 + SWZ(t, d)]       = (_Float16)(qf * egt);
      SAu[12288 + SWZ(d, t)]      = (_Float16)(kf * ekt);
    }
    const ushort* vrow = vc + ((size_t)bh * TT + c0 + t) * 128 + dg * 32;
    half8v v0 = *(const half8v*)(vrow),      v1 = *(const half8v*)(vrow + 8);
    half8v v2 = *(const half8v*)(vrow + 16), v3 = *(const half8v*)(vrow + 24);
#pragma unroll
    for (int e = 0; e < 8; ++e) {
      VT[(dg * 32 + e) * 72 + t]      = v0[e];
      VT[(dg * 32 + 8 + e) * 72 + t]  = v1[e];
      VT[(dg * 32 + 16 + e) * 72 + t] = v2[e];
      VT[(dg * 32 + 24 + e) * 72 + t] = v3[e];
    }
    for (int i = tid; i < 64 * 67; i += 256) Tg[i] = 0.f;
  }
  __syncthreads();

  // ph2: A and P
  {
    f32x4 accA[2][2], accP[2][2];
    gemm64(Kf, 72, Kf, 72, wr, wc, lane, 2, 0, accA);
    gemm64(Qf, 72, Kf, 72, wr, wc, lane, 2, 0, accP);
#pragma unroll
    for (int m = 0; m < 2; ++m)
#pragma unroll
      for (int n = 0; n < 2; ++n)
#pragma unroll
        for (int j = 0; j < 4; ++j) {
          const int row = wr * 32 + m * 16 + (lane >> 4) * 4 + j;
          const int col = wc * 32 + n * 16 + (lane & 15);
          const float eg = expf(g_s[row] - g_s[col]);
          Af[row * 67 + col] = (col < row) ? bet_s[row] * eg * accA[m][n][j] : 0.f;
          SAu[4096 + SWZ(row, col)] =
              (col <= row) ? (_Float16)(eg * accP[m][n][j]) : (_Float16)0.f;
        }
  }
  __syncthreads();

  // ph3a
  if (lane < 16) {
    const int R = w * 16;
    Tg[R * 67 + R + lane] = (lane == 0) ? 1.f : 0.f;
    for (int t = 1; t < 16; ++t) {
      float s = 0.f;
      for (int i = 0; i < t; ++i)
        s = fmaf(Af[(R + t) * 67 + R + i], Tg[(R + i) * 67 + R + lane], s);
      Tg[(R + t) * 67 + R + lane] = ((lane == t) ? 1.f : 0.f) - s;
    }
  }
  __syncthreads();
  // ph3b-1
  {
    const int r = (tid >> 4) & 15, cx = tid & 15;
#pragma unroll
    for (int p = 0; p < 2; ++p) {
      float s = 0.f;
      for (int i = 0; i < 16; ++i)
        s = fmaf(Af[(p * 32 + 16 + r) * 67 + p * 32 + i],
                 Tg[(p * 32 + i) * 67 + p * 32 + cx], s);
      tmpf[p * 272 + r * 17 + cx] = s;
    }
  }
  __syncthreads();
  // ph3b-2
  {
    const int r = (tid >> 4) & 15, cx = tid & 15;
#pragma unroll
    for (int p = 0; p < 2; ++p) {
      float s = 0.f;
      for (int i = 0; i < 16; ++i)
        s = fmaf(Tg[(p * 32 + 16 + r) * 67 + p * 32 + 16 + i],
                 tmpf[p * 272 + i * 17 + cx], s);
      Tg[(p * 32 + 16 + r) * 67 + p * 32 + cx] = -s;
    }
  }
  __syncthreads();
  // ph3c-1
  {
#pragma unroll
    for (int rep = 0; rep < 4; ++rep) {
      const int idx = tid + rep * 256;
      const int r = idx >> 5, cx = idx & 31;
      float s = 0.f;
      for (int i = 0; i < 32; ++i)
        s = fmaf(Af[(32 + r) * 67 + i], Tg[i * 67 + cx], s);
      tmpf[r * 33 + cx] = s;
    }
  }
  __syncthreads();
  // ph3c-2
  {
#pragma unroll
    for (int rep = 0; rep < 4; ++rep) {
      const int idx = tid + rep * 256;
      const int r = idx >> 5, cx = idx & 31;
      float s = 0.f;
      for (int i = 0; i < 32; ++i)
        s = fmaf(Tg[(32 + r) * 67 + 32 + i], tmpf[i * 33 + cx], s);
      Tg[(32 + r) * 67 + cx] = -s;
    }
  }
  __syncthreads();

  // ph4: cast Tg -> Tf
  {
    const int t = tid >> 2, qg = tid & 3;
#pragma unroll
    for (int e = 0; e < 16; ++e) {
      const int i = qg * 16 + e;
      Tf[t * 72 + i] = (_Float16)Tg[t * 67 + i];
    }
  }
  __syncthreads();

  // ph5: W, Z -> scratch (SWZ layout)
  {
    f32x4 accW[2][2];
    gemm64(Tf, 72, KbT, 72, wr, wc, lane, 2, 0, accW);
#pragma unroll
    for (int m = 0; m < 2; ++m)
#pragma unroll
      for (int n = 0; n < 2; ++n)
#pragma unroll
        for (int j = 0; j < 4; ++j) {
          const int row = wr * 32 + m * 16 + (lane >> 4) * 4 + j;
          const int col = wc * 32 + n * 16 + (lane & 15);
          SAu[SWZ(row, col)] = (_Float16)accW[m][n][j];
        }
#pragma unroll
    for (int H = 0; H < 2; ++H) {
      f32x4 accZ[2][2];
      gemm64(Tf, 72, VT + H * 64 * 72, 72, wr, wc, lane, 2, 0, accZ);
#pragma unroll
      for (int m = 0; m < 2; ++m)
#pragma unroll
        for (int n = 0; n < 2; ++n)
#pragma unroll
          for (int j = 0; j < 4; ++j) {
            const int row = wr * 32 + m * 16 + (lane >> 4) * 4 + j;
            const int col = wc * 32 + n * 16 + (lane & 15);
            SAu[16384 + H * 4096 + SWZ(row, col)] = (_Float16)accZ[m][n][j];
          }
    }
  }
}

// ---------------------------------------------------------------------------
// Scan phase B (R23-proven): gload_lds double-buffer, counted vmcnt.
// ---------------------------------------------------------------------------
__global__ __launch_bounds__(256) void scan_phaseB(
    const _Float16* __restrict__ SA, const float* __restrict__ egCg,
    float* __restrict__ o)
{
  __shared__ float    Sf[64 * 65];
  __shared__ ushort   B0[20480];
  __shared__ ushort   B1[20480];
  __shared__ _Float16 Y2[64 * 144];
  __shared__ float    egc_l[16];

  const int blk  = blockIdx.x;
  const int bh   = blk % NBH;
  const int H    = blk / NBH;
  const int b    = bh / HH, h = bh % HH;
  const int tid  = threadIdx.x;
  const int lane = tid & 63;
  const int w    = tid >> 6;
  const int wr   = w >> 1, wc = w & 1;

  for (int i = tid; i < 64 * 65; i += 256) Sf[i] = 0.f;
  if (tid < 16) egc_l[tid] = egCg[tid * NBH + bh];

#define STG(DST, CC) do { \
    const ushort* ub = (const ushort*)SA + (size_t)((CC) * NBH + bh) * 24576; \
    _Pragma("unroll") \
    for (int j = 0; j < 8; ++j) { \
      const int g = j * 4 + w; \
      gload16(ub + g * 512 + lane * 8, &DST[g * 512]); \
    } \
    _Pragma("unroll") \
    for (int j = 8; j < 10; ++j) { \
      const int g = j * 4 + w; \
      gload16(ub + 16384 + H * 4096 + (g - 32) * 512 + lane * 8, &DST[g * 512]); \
    } \
  } while (0)

  STG(B0, 0);
  __syncthreads();

#define BODY(CURB, NXTB, CC) do { \
    if ((CC) + 1 < 16) STG(NXTB, (CC) + 1); \
    { const int v = tid >> 2, ds2 = tid & 3; \
      _Pragma("unroll") \
      for (int e = 0; e < 16; ++e) \
        Y2[v * 144 + ds2 * 16 + e] = (_Float16)Sf[v * 65 + ds2 * 16 + e]; } \
    if ((CC) + 1 < 16) asm volatile("s_waitcnt vmcnt(26) lgkmcnt(0)" ::: "memory"); \
    else               asm volatile("s_waitcnt vmcnt(16) lgkmcnt(0)" ::: "memory"); \
    __builtin_amdgcn_s_barrier(); \
    __builtin_amdgcn_sched_barrier(0); \
    { f32x4 accU[2][2]; \
      _Pragma("unroll") \
      for (int m = 0; m < 2; ++m) \
        _Pragma("unroll") \
        for (int n = 0; n < 2; ++n) \
          _Pragma("unroll") \
          for (int j = 0; j < 4; ++j) accU[m][n][j] = 0.f; \
      gemm64x(CURB, Y2, 144, wr, wc, lane, accU); \
      _Pragma("unroll") \
      for (int m = 0; m < 2; ++m) \
        _Pragma("unroll") \
        for (int n = 0; n < 2; ++n) \
          _Pragma("unroll") \
          for (int j = 0; j < 4; ++j) { \
            const int row = wr * 32 + m * 16 + (lane >> 4) * 4 + j; \
            const int col = wc * 32 + n * 16 + (lane & 15); \
            const float zv = h2f(CURB[16384 + SWZ(row, col)]); \
            Y2[col * 144 + 72 + row] = (_Float16)(zv - accU[m][n][j]); \
          } } \
    asm volatile("s_waitcnt lgkmcnt(0)" ::: "memory"); \
    __builtin_amdgcn_s_barrier(); \
    __builtin_amdgcn_sched_barrier(0); \
    { f32x4 accS[2][2], accO[2][2]; \
      _Pragma("unroll") \
      for (int m = 0; m < 2; ++m) \
        _Pragma("unroll") \
        for (int n = 0; n < 2; ++n) \
          _Pragma("unroll") \
          for (int j = 0; j < 4; ++j) { accS[m][n][j] = 0.f; accO[m][n][j] = 0.f; } \
      gemm64x(CURB + 12288, Y2 + 72, 144, wr, wc, lane, accS); \
      gemm64x(CURB + 8192,  Y2,      144, wr, wc, lane, accO); \
      gemm64x(CURB + 4096,  Y2 + 72, 144, wr, wc, lane, accO); \
      const float egC = egc_l[(CC)]; \
      _Pragma("unroll") \
      for (int m = 0; m < 2; ++m) \
        _Pragma("unroll") \
        for (int n = 0; n < 2; ++n) \
          _Pragma("unroll") \
          for (int j = 0; j < 4; ++j) { \
            const int row = wr * 32 + m * 16 + (lane >> 4) * 4 + j; \
            const int col = wc * 32 + n * 16 + (lane & 15); \
            Sf[col * 65 + row] = egC * Sf[col * 65 + row] + accS[m][n][j]; \
            o[(((size_t)b * TT + (CC) * 64 + row) * HH + h) * 128 + H * 64 + col] = accO[m][n][j]; \
          } } \
    asm volatile("s_waitcnt lgkmcnt(0)" ::: "memory"); \
    __builtin_amdgcn_s_barrier(); \
    __builtin_amdgcn_sched_barrier(0); \
  } while (0)

  for (int cp = 0; cp < 8; ++cp) {
    BODY(B0, B1, 2 * cp);
    BODY(B1, B0, 2 * cp + 1);
  }
#undef STG
#undef BODY
}

// ---------------------------------------------------------------------------
// RMS norm over 128 + SiLU gate; reads f16 g16; emits fp16 for final GEMM.
// ---------------------------------------------------------------------------
__global__ void rmsgate_kernel(const float* __restrict__ o, const ushort* __restrict__ g16,
                               ushort* __restrict__ gof)
{
  int gid  = blockIdx.x * blockDim.x + threadIdx.x;
  int wid  = gid >> 6;
  int lane = threadIdx.x & 63;
  if (wid >= BB * TT * HH) return;
  int h = wid % HH;
  int m = wid / HH;
  const float* orow = o + (size_t)wid * 128;
  float2 ov = *(const float2*)(orow + lane * 2);
  float ss = ov.x * ov.x + ov.y * ov.y;
#pragma unroll
  for (int mm = 32; mm >= 1; mm >>= 1) ss += __shfl_xor(ss, mm, 64);
  float scale = rsqrtf(ss * (1.f / 128.f) + EPSF);
  const ushort* gr = g16 + (size_t)m * TVv + h * 128 + lane * 2;
  float o0 = ov.x * scale * siluf(h2f(gr[0]));
  float o1 = ov.y * scale * siluf(h2f(gr[1]));
  *(uint*)(gof + (size_t)m * TVv + h * 128 + lane * 2) = pk2h(o0, o1);
}

// ---------------------------------------------------------------------------
extern "C" void kernel_launch(void* const* d_in, const int* in_sizes, int n_in,
                              void* d_out, int out_size, void* d_ws, size_t ws_size,
                              hipStream_t stream) {
  (void)in_sizes; (void)n_in; (void)out_size; (void)ws_size;
  const float* x       = (const float*)d_in[0];
  const float* w_q     = (const float*)d_in[1];
  const float* w_k     = (const float*)d_in[2];
  const float* w_v     = (const float*)d_in[3];
  const float* w_a     = (const float*)d_in[4];
  const float* w_b     = (const float*)d_in[5];
  const float* w_g     = (const float*)d_in[6];
  const float* w_out   = (const float*)d_in[7];
  const float* A_log   = (const float*)d_in[8];
  const float* dt_bias = (const float*)d_in[9];
  const float* qcw     = (const float*)d_in[10];
  const float* kcw     = (const float*)d_in[11];
  const float* vcw     = (const float*)d_in[12];

  float* ws  = (float*)d_ws;
  float* abi = ws + 15728640;

  ushort* xf    = (ushort*)(ws + 9437184);
  ushort* wcat  = (ushort*)(ws + 9437184 + 1572864);

  ushort* pA = (ushort*)ws;
  ushort* pB = (ushort*)(ws + 4718592);

  ushort* qc16 = (ushort*)(ws + 9437184);
  ushort* kc16 = (ushort*)(ws + 9437184 + 786432);
  ushort* vc16 = (ushort*)(ws + 9437184 + 1572864);
  ushort* g16  = (ushort*)(ws + 9437184 + 3145728);
  ushort* gof  = (ushort*)(ws + 9437184 + 4718592);

  _Float16* SA   = (_Float16*)ws;
  float*    egCg = ws + 4718592;
  float*    o    = ws + 4719104;
  ushort*   woutf = (ushort*)(ws + 7864832);
  ushort*   fp4   = (ushort*)ws;

  const int M = BB * TT;  // 2048
  dim3 blk(256);

  // 1) fp16 casts
  cast_f16_kernel<<<1536, blk, 0, stream>>>(x, xf);
  cast_w4_kernel<<<3456, blk, 0, stream>>>(w_q, w_k, w_v, w_g, wcat);

  // 2) fused qkv+g projection, K-split-2
  gemm_f16_ks<DD, DD / 2, 2><<<1152, blk, 0, stream>>>(xf, wcat, pA, M, NQKVG);

  // 3) gating coefficients
  gate_kernel<<<M, blk, 0, stream>>>(x, w_a, w_b, A_log, dt_bias, abi);

  // 4) conv + SiLU + L2 norm + g-fold (vectorized: 8 cols/thread)
  conv_silu_kernel<<<4608, blk, 0, stream>>>(pA, pB, qcw, kcw, vcw,
                                             qc16, kc16, vc16, g16);

  // 5) scan
  scan_phaseA<<<16 * NBH, blk, 0, stream>>>(qc16, kc16, vc16, abi, SA, egCg);
  scan_phaseB<<<2 * NBH, blk, 0, stream>>>(SA, egCg, o);

  // 6) cast w_out
  cast_f16_kernel<<<1152, blk, 0, stream>>>(w_out, woutf);

  // 7) RMS norm + SiLU gate
  rmsgate_kernel<<<6144, blk, 0, stream>>>(o, g16, gof);

  // 8) output projection, K-split-4
  gemm_f16_ks<DD, DD / 4, 4><<<768, blk, 0, stream>>>(gof, woutf, fp4, M, TVv);

  // 9) reduce partials
  reduce4_kernel<<<1536, blk, 0, stream>>>(fp4, (float*)d_out);
}